// Round 14
// baseline (205.305 us; speedup 1.0000x reference)
//
#include <hip/hip_runtime.h>

// EGNN layer, round 22: dispatch consolidation. init_k eliminated —
// W1t transform inlined into pgemm's LDS staging (pe_w1 read direct);
// Wp1t/Wp2t/w2h transforms run as extra blocks (1024..1107) of the mega
// launch (consumed only by LATER kernels — race-free). Pipeline is now
// memset -> mega(pgemm+scatter+transforms) -> node -> mlp = 4 dispatches.
// node_k: proven r16 single-edge loop + gjv adjacency preload/readlane
// (removes 1 VMEM/edge; r12/r18-proven pattern). pgemm/mlp = r21 forms.
// B=4, N=16384, E=65536, DH=128, DM=64.  NB = 65536 global nodes.

typedef unsigned short ushort_t;
typedef __attribute__((ext_vector_type(8))) short bf16x8;
typedef __attribute__((ext_vector_type(4))) float f32x4;
typedef _Float16 h2 __attribute__((ext_vector_type(2)));

__device__ __forceinline__ float fast_rcp(float v) { return __builtin_amdgcn_rcpf(v); }
__device__ __forceinline__ float fast_silu(float v) { return v * fast_rcp(1.0f + __expf(-v)); }
__device__ __forceinline__ ushort_t f2bf(float f) {
    unsigned u = __float_as_uint(f);
    u += 0x7fffu + ((u >> 16) & 1u);
    return (ushort_t)(u >> 16);
}
__device__ __forceinline__ float bf2f(ushort_t b) {
    return __uint_as_float(((unsigned)b) << 16);
}
__device__ __forceinline__ h2 u2h2(unsigned u) {
    union { unsigned u; h2 h; } v; v.u = u; return v.h;
}

// ---------------------------------------------------------------------------
// mega kernel, 512 threads/block:
//  blocks    0..511 : pgemm  P = h @ W1fused^T (bf16), emits hb=bf16(h).
//                     B staged k-sliced into LDS with INLINE transform from
//                     pe_w1 (no W1t buffer). A direct from global. 1 barrier.
//  blocks  512..1023: scatter elist[gi*64+slot]=gj (512 thr x 512 blk = 256Ki)
//  blocks 1024..1107: weight transforms Wp1t / Wp2t / w2h (43008 items)
// ---------------------------------------------------------------------------
template <bool EMIT_BF16>
__global__ __launch_bounds__(512) void mega_k(const float* __restrict__ A0,
                                              const float* __restrict__ pe_w1,
                                              ushort_t* __restrict__ outP,
                                              ushort_t* __restrict__ hbout,
                                              const int* __restrict__ ei,
                                              int* __restrict__ cursor,
                                              int* __restrict__ elist,
                                              const float* __restrict__ pe_w2,
                                              const float* __restrict__ ph_w1,
                                              const float* __restrict__ ph_w2,
                                              ushort_t* __restrict__ Wp1t,
                                              ushort_t* __restrict__ Wp2t,
                                              unsigned* __restrict__ w2h) {
    __shared__ ushort_t Bs[16384];                 // [kg=16][row=128][8] = 32 KB
    const int tid = threadIdx.x;

    if (blockIdx.x >= 1024) {                      // ---- weight transforms
        int g = (blockIdx.x - 1024) * 512 + tid;
        if (g < 24576) {
            int n = g / 192, k = g - n * 192;
            Wp1t[g] = f2bf(ph_w1[k * 128 + n]);
        } else if (g < 40960) {
            int g3 = g - 24576;
            int n = g3 >> 7, k = g3 & 127;
            Wp2t[g3] = f2bf(ph_w2[k * 128 + n]);
        } else if (g < 43008) {
            int g4 = g - 40960;
            int k2 = g4 >> 6, c = g4 & 63;
            union { unsigned u; _Float16 h[2]; } p;
            p.h[0] = (_Float16)pe_w2[(2 * k2) * 64 + c];
            p.h[1] = (_Float16)pe_w2[(2 * k2 + 1) * 64 + c];
            w2h[g4] = p.u;
        }
        return;
    }

    if (blockIdx.x >= 512) {                       // ---- scatter part
        int e = (blockIdx.x - 512) * 512 + tid;
        int2 sd = ((const int2*)ei)[e];
        int b = e >> 16;
        int gi = (b << 14) + sd.x;
        int gj = (b << 14) + sd.y;
        int slot = atomicAdd(&cursor[gi], 1);
        if (slot < 64) elist[gi * 64 + slot] = gj;
        return;
    }

    // ---- pgemm part
    const int m0 = blockIdx.x * 128;
    const int wave = tid >> 6;                     // 0..7
    const int lane = tid & 63;
    const int lr = lane & 15;
    const int lq = lane >> 4;

    // stage fused-W1 k-sliced, transforming from pe_w1 on the fly:
    // Bs[kg][n][0..7] = bf16(W1[n][kg*8+j]);  W1[n][k] = pe_w1[k*64+n] (n<64)
    //                                                 or pe_w1[(128+k)*64+n-64]
#pragma unroll
    for (int i = 0; i < 4; i++) {
        int c = tid + i * 512;
        int n = c >> 4, kg = c & 15;
        const float* src = (n < 64) ? (pe_w1 + n) : (pe_w1 + 128 * 64 + (n - 64));
        union { ushort_t s[8]; uint4 u; } p;
#pragma unroll
        for (int j = 0; j < 8; j++)
            p.s[j] = f2bf(src[(kg * 8 + j) * 64]);
        *(uint4*)&Bs[kg * 1024 + n * 8] = p.u;
    }
    __syncthreads();                               // the ONLY barrier

    f32x4 acc[8];
#pragma unroll
    for (int nt = 0; nt < 8; nt++) { f32x4 z = {0.f,0.f,0.f,0.f}; acc[nt] = z; }

    for (int k0 = 0; k0 < 128; k0 += 32) {
        int row = m0 + wave * 16 + lr;
        const float* src = A0 + (size_t)row * 128 + k0 + lq * 8;
        float4 v0 = *(const float4*)src;
        float4 v1 = *(const float4*)(src + 4);
        union { ushort_t s[8]; bf16x8 v; uint4 u; } p;
        p.s[0] = f2bf(v0.x); p.s[1] = f2bf(v0.y);
        p.s[2] = f2bf(v0.z); p.s[3] = f2bf(v0.w);
        p.s[4] = f2bf(v1.x); p.s[5] = f2bf(v1.y);
        p.s[6] = f2bf(v1.z); p.s[7] = f2bf(v1.w);
        if (EMIT_BF16)
            *(uint4*)(hbout + (size_t)row * 128 + k0 + lq * 8) = p.u;
        bf16x8 af = p.v;
        bf16x8 bfr[8];
        int kg = (k0 >> 3) + lq;
#pragma unroll
        for (int nt = 0; nt < 8; nt++)
            bfr[nt] = *(const bf16x8*)&Bs[kg * 1024 + (nt * 16 + lr) * 8];
#pragma unroll
        for (int nt = 0; nt < 8; nt++)
            acc[nt] = __builtin_amdgcn_mfma_f32_16x16x32_bf16(af, bfr[nt], acc[nt], 0, 0, 0);
    }
#pragma unroll
    for (int nt = 0; nt < 8; nt++)
#pragma unroll
        for (int r = 0; r < 4; r++) {
            int row = m0 + wave * 16 + lq * 4 + r;
            int col = nt * 16 + lr;
            outP[(size_t)row * 128 + col] = f2bf(acc[nt][r]);
        }
}

// ---------------------------------------------------------------------------
// node kernel: r16 proven single-edge loop + gjv adjacency preload (one
// coalesced 256B load/wave; per-edge index via readlane — removes the
// per-edge elist VMEM load). Register prefetch of next edge's gathers.
// ---------------------------------------------------------------------------
__global__ __launch_bounds__(64, 4) void node_k(const float* __restrict__ x,
                                                const ushort_t* __restrict__ P,
                                                const int* __restrict__ cursor,
                                                const int* __restrict__ elist,
                                                const float* __restrict__ w1,
                                                const float* __restrict__ b1,
                                                const unsigned* __restrict__ w2h,
                                                const float* __restrict__ b2,
                                                const float* __restrict__ pxw,
                                                ushort_t* __restrict__ dh,
                                                float* __restrict__ outx) {
    const int n = blockIdx.x;
    const int lane = threadIdx.x;
    __shared__ __attribute__((aligned(16))) unsigned m_u[32];    // 64 halves
    ushort_t* mh = (ushort_t*)m_u;

    const float w1r = w1[256 * 64 + lane];       // dist2 row of pe_w1
    const float b2v = b2[lane];
    const float pxv = pxw[lane];
    const float Pib = bf2f(P[(size_t)n * 128 + lane]) + b1[lane];
    const float xi0 = x[n * 3 + 0];
    const float xi1 = x[n * 3 + 1];
    const float xi2 = x[n * 3 + 2];

    float dhacc = 0.0f;
    float dxp0 = 0.0f, dxp1 = 0.0f, dxp2 = 0.0f;
    const int dg = min(cursor[n], 64);

    // coalesced preload of the whole adjacency row (one 256B load / wave);
    // lanes >= dg hold 0 (a valid node index) so stray prefetches are safe.
    int gjv = 0;
    if (lane < dg) gjv = elist[n * 64 + lane];

    int gj = __builtin_amdgcn_readlane(gjv, 0);
    float Pj = bf2f(P[(size_t)gj * 128 + 64 + lane]);
    float xj0 = x[gj * 3 + 0];
    float xj1 = x[gj * 3 + 1];
    float xj2 = x[gj * 3 + 2];

    for (int t = 0; t < dg; t++) {
        int gjn = __builtin_amdgcn_readlane(gjv, (t + 1) & 63);
        float Pjn = bf2f(P[(size_t)gjn * 128 + 64 + lane]);
        float xn0 = x[gjn * 3 + 0];
        float xn1 = x[gjn * 3 + 1];
        float xn2 = x[gjn * 3 + 2];

        float ddx = xi0 - xj0;
        float ddy = xi1 - xj1;
        float ddz = xi2 - xj2;
        float d2 = fmaxf(ddx * ddx + ddy * ddy + ddz * ddz, 1e-12f);
        float m = fast_silu(Pib + Pj + d2 * w1r);
        __builtin_amdgcn_wave_barrier();
        union { ushort_t s; _Float16 h; } mc;
        mc.h = (_Float16)m;
        mh[lane] = mc.s;
        __builtin_amdgcn_wave_barrier();
        float s0 = b2v, s1 = 0.0f, s2 = 0.0f, s3 = 0.0f;
#pragma unroll
        for (int q = 0; q < 8; q++) {
            uint4 mm = *(const uint4*)&m_u[q * 4];               // ds_read_b128 broadcast
            s0 = __builtin_amdgcn_fdot2(u2h2(mm.x), u2h2(w2h[(4 * q + 0) * 64 + lane]), s0, false);
            s1 = __builtin_amdgcn_fdot2(u2h2(mm.y), u2h2(w2h[(4 * q + 1) * 64 + lane]), s1, false);
            s2 = __builtin_amdgcn_fdot2(u2h2(mm.z), u2h2(w2h[(4 * q + 2) * 64 + lane]), s2, false);
            s3 = __builtin_amdgcn_fdot2(u2h2(mm.w), u2h2(w2h[(4 * q + 3) * 64 + lane]), s3, false);
        }
        __builtin_amdgcn_wave_barrier();
        float m2 = fast_silu((s0 + s1) + (s2 + s3));
        dhacc += m2;
        float c = m2 * pxv * fast_rcp(sqrtf(d2) + 1e-8f);
        dxp0 = fmaf(c, ddx, dxp0);
        dxp1 = fmaf(c, ddy, dxp1);
        dxp2 = fmaf(c, ddz, dxp2);

        Pj = Pjn; xj0 = xn0; xj1 = xn1; xj2 = xn2;
    }

    dh[(size_t)n * 64 + lane] = f2bf(dhacc);                 // coalesced

    for (int off = 32; off; off >>= 1) {
        dxp0 += __shfl_down(dxp0, off);
        dxp1 += __shfl_down(dxp1, off);
        dxp2 += __shfl_down(dxp2, off);
    }
    if (lane == 0) {
        outx[n * 3 + 0] = xi0 + dxp0;
        outx[n * 3 + 1] = xi1 + dxp1;
        outx[n * 3 + 2] = xi2 + dxp2;
    }
}

// ---------------------------------------------------------------------------
// Fused node MLP, 512 threads (8 waves, 16-row band per wave, 1x8 acc).
// B (Wp1t then Wp2t) in LDS once per phase, k-sliced. A direct from global.
// Ts k-sliced, per-wave row banding. Barriers: 3 total.
// ---------------------------------------------------------------------------
template <bool USE_HB>
__global__ __launch_bounds__(512) void mlp_fused_k(const float* __restrict__ h,
                                                   const ushort_t* __restrict__ hb,
                                                   const ushort_t* __restrict__ dh,
                                                   const ushort_t* __restrict__ Wp1t,
                                                   const float* __restrict__ b1,
                                                   const ushort_t* __restrict__ Wp2t,
                                                   const float* __restrict__ b2,
                                                   float* __restrict__ outh) {
    __shared__ ushort_t Ws[24576];   // phase1: [kg=24][128][8] = 48 KB; phase2: 16 kg
    __shared__ ushort_t Ts[16384];   // [kg=16][128][8] = 32 KB
    const int tid = threadIdx.x;
    const int m0 = blockIdx.x * 128;
    const int wave = tid >> 6;       // 0..7
    const int lane = tid & 63;
    const int lr = lane & 15;
    const int lq = lane >> 4;

    // stage Wp1t k-sliced: chunk c -> kg = c>>7 (0..23), n = c&127
#pragma unroll
    for (int i = 0; i < 6; i++) {
        int c = tid + i * 512;
        int kg = c >> 7, n = c & 127;
        *(uint4*)&Ws[kg * 1024 + n * 8] = *(const uint4*)(Wp1t + (size_t)n * 192 + kg * 8);
    }
    __syncthreads();                               // barrier 1

    // ---- phase 1: t = silu([h|dh] @ W1 + b1), K = 192, A direct
    f32x4 acc[8];
#pragma unroll
    for (int nt = 0; nt < 8; nt++) { f32x4 z = {0.f,0.f,0.f,0.f}; acc[nt] = z; }

    for (int k0 = 0; k0 < 192; k0 += 32) {
        int row = m0 + wave * 16 + lr;
        int k = k0 + lq * 8;
        bf16x8 af;
        if (k >= 128) {
            af = *(const bf16x8*)&dh[(size_t)row * 64 + (k - 128)];
        } else if (USE_HB) {
            af = *(const bf16x8*)&hb[(size_t)row * 128 + k];
        } else {
            const float* src = h + (size_t)row * 128 + k;
            float4 v0 = *(const float4*)src;
            float4 v1 = *(const float4*)(src + 4);
            union { ushort_t s[8]; bf16x8 v; } p;
            p.s[0] = f2bf(v0.x); p.s[1] = f2bf(v0.y);
            p.s[2] = f2bf(v0.z); p.s[3] = f2bf(v0.w);
            p.s[4] = f2bf(v1.x); p.s[5] = f2bf(v1.y);
            p.s[6] = f2bf(v1.z); p.s[7] = f2bf(v1.w);
            af = p.v;
        }
        bf16x8 bfr[8];
        int kg = (k0 >> 3) + lq;
#pragma unroll
        for (int nt = 0; nt < 8; nt++)
            bfr[nt] = *(const bf16x8*)&Ws[kg * 1024 + (nt * 16 + lr) * 8];
#pragma unroll
        for (int nt = 0; nt < 8; nt++)
            acc[nt] = __builtin_amdgcn_mfma_f32_16x16x32_bf16(af, bfr[nt], acc[nt], 0, 0, 0);
    }
    // epilogue 1: silu -> Ts (k-sliced; rows wave*16..+15 are wave-private)
#pragma unroll
    for (int nt = 0; nt < 8; nt++)
#pragma unroll
        for (int r = 0; r < 4; r++) {
            int row = wave * 16 + lq * 4 + r;
            int col = nt * 16 + lr;
            Ts[(col >> 3) * 1024 + row * 8 + (col & 7)] =
                f2bf(fast_silu(acc[nt][r] + b1[col]));
        }
    __builtin_amdgcn_wave_barrier();

    // swap Ws -> Wp2t (all waves must be done reading Wp1t)
    __syncthreads();                               // barrier 2
#pragma unroll
    for (int i = 0; i < 4; i++) {
        int c = tid + i * 512;
        int kg = c >> 7, n = c & 127;
        *(uint4*)&Ws[kg * 1024 + n * 8] = *(const uint4*)(Wp2t + (size_t)n * 128 + kg * 8);
    }
    __syncthreads();                               // barrier 3

    // ---- phase 2: out = t @ W2 + b2 + h, K = 128, A from Ts (own band)
    f32x4 acc2[8];
#pragma unroll
    for (int nt = 0; nt < 8; nt++) { f32x4 z = {0.f,0.f,0.f,0.f}; acc2[nt] = z; }

    for (int k0 = 0; k0 < 128; k0 += 32) {
        int kg = (k0 >> 3) + lq;
        bf16x8 af = *(const bf16x8*)&Ts[kg * 1024 + (wave * 16 + lr) * 8];
        bf16x8 bfr[8];
#pragma unroll
        for (int nt = 0; nt < 8; nt++)
            bfr[nt] = *(const bf16x8*)&Ws[kg * 1024 + (nt * 16 + lr) * 8];
#pragma unroll
        for (int nt = 0; nt < 8; nt++)
            acc2[nt] = __builtin_amdgcn_mfma_f32_16x16x32_bf16(af, bfr[nt], acc2[nt], 0, 0, 0);
    }
    // epilogue 2: + b2 + h residual
#pragma unroll
    for (int nt = 0; nt < 8; nt++)
#pragma unroll
        for (int r = 0; r < 4; r++) {
            int row = m0 + wave * 16 + lq * 4 + r;
            int col = nt * 16 + lr;
            float v = acc2[nt][r] + b2[col];
            if (USE_HB) v += bf2f(hb[(size_t)row * 128 + col]);
            else        v += h[(size_t)row * 128 + col];
            outh[(size_t)row * 128 + col] = v;
        }
}

// ---------------------------------------------------------------------------
extern "C" void kernel_launch(void* const* d_in, const int* in_sizes, int n_in,
                              void* d_out, int out_size, void* d_ws, size_t ws_size,
                              hipStream_t stream) {
    const float* x     = (const float*)d_in[0];
    const float* h     = (const float*)d_in[1];
    const int*   ei    = (const int*)d_in[2];
    const float* pe_w1 = (const float*)d_in[3];
    const float* pe_b1 = (const float*)d_in[4];
    const float* pe_w2 = (const float*)d_in[5];
    const float* pe_b2 = (const float*)d_in[6];
    const float* px_w  = (const float*)d_in[7];
    const float* ph_w1 = (const float*)d_in[8];
    const float* ph_b1 = (const float*)d_in[9];
    const float* ph_w2 = (const float*)d_in[10];
    const float* ph_b2 = (const float*)d_in[11];

    float* outx = (float*)d_out;                    // 4*16384*3
    float* outh = (float*)d_out + 196608;           // 4*16384*128

    // ws layout (W1t slot retained but unused — keeps offsets stable)
    ushort_t* P    = (ushort_t*)d_ws;                     // 65536*128 bf16
    ushort_t* dh   = P + (size_t)65536 * 128;             // 65536*64 bf16
    int* cursor    = (int*)(dh + (size_t)65536 * 64);     // 65536 i32
    int* elist     = cursor + 65536;                      // 65536*64 i32 (16 MB)
    ushort_t* W1t  = (ushort_t*)(elist + (size_t)65536 * 64);  // (unused)
    ushort_t* Wp1t = W1t + 16384;                         // 128*192 bf16
    ushort_t* Wp2t = Wp1t + 24576;                        // 128*128 bf16
    unsigned* w2h  = (unsigned*)(Wp2t + 16384);           // 32*64 uint (in 16KB slot)
    ushort_t* hb   = (ushort_t*)(w2h + 4096);             // 65536*128 bf16 (16 MB)
    size_t need_hb = (size_t)((char*)(hb + (size_t)65536 * 128) - (char*)d_ws);
    const bool use_hb = ws_size >= need_hb;

    hipMemsetAsync(cursor, 0, 65536 * sizeof(int), stream);
    if (use_hb)
        mega_k<true><<<1108, 512, 0, stream>>>(h, pe_w1, P, hb, ei, cursor, elist,
                                               pe_w2, ph_w1, ph_w2, Wp1t, Wp2t, w2h);
    else
        mega_k<false><<<1108, 512, 0, stream>>>(h, pe_w1, P, nullptr, ei, cursor, elist,
                                                pe_w2, ph_w1, ph_w2, Wp1t, Wp2t, w2h);
    node_k<<<65536, 64, 0, stream>>>(x, P, cursor, elist,
                                     pe_w1, pe_b1, w2h, pe_b2, px_w,
                                     dh, outx);
    if (use_hb)
        mlp_fused_k<true><<<512, 512, 0, stream>>>(h, hb, dh, Wp1t, ph_b1,
                                                   Wp2t, ph_b2, outh);
    else
        mlp_fused_k<false><<<512, 512, 0, stream>>>(h, nullptr, dh, Wp1t, ph_b1,
                                                    Wp2t, ph_b2, outh);
}

// Round 15
// 189.299 us; speedup vs baseline: 1.0845x; 1.0845x over previous
//
#include <hip/hip_runtime.h>

// EGNN layer, round 23 = r19 restored verbatim (best measured: 190.6 us).
// r16 base + scatter fused into the pgemm launch. node_k = proven 60-us
// single-edge loop w/ register prefetch (issue-bound floor; 7 variants all
// worse). GEMMs = staged 256-thread forms (barrier/TLP/staging restructures
// r17/r20/r21/r22 all neutral-to-worse). This banks the session's best.
// B=4, N=16384, E=65536, DH=128, DM=64.  NB = 65536 global nodes.

typedef unsigned short ushort_t;
typedef __attribute__((ext_vector_type(8))) short bf16x8;
typedef __attribute__((ext_vector_type(4))) float f32x4;
typedef _Float16 h2 __attribute__((ext_vector_type(2)));

__device__ __forceinline__ float fast_rcp(float v) { return __builtin_amdgcn_rcpf(v); }
__device__ __forceinline__ float fast_silu(float v) { return v * fast_rcp(1.0f + __expf(-v)); }
__device__ __forceinline__ ushort_t f2bf(float f) {
    unsigned u = __float_as_uint(f);
    u += 0x7fffu + ((u >> 16) & 1u);
    return (ushort_t)(u >> 16);
}
__device__ __forceinline__ float bf2f(ushort_t b) {
    return __uint_as_float(((unsigned)b) << 16);
}
__device__ __forceinline__ h2 u2h2(unsigned u) {
    union { unsigned u; h2 h; } v; v.u = u; return v.h;
}

// ---------------------------------------------------------------------------
// init: cursor=0 (65536) + weight transforms. 488*256 = 124928 threads exact.
//  W1t  bf16[128][128] : fused pe_w1 cols, k-contiguous
//  Wp1t bf16[128][192] : ph_w1^T
//  Wp2t bf16[128][128] : ph_w2^T
//  w2h  uint[32][64]   : w2h[k2*64+c] = half2(pe_w2[2k2][c], pe_w2[2k2+1][c])
// ---------------------------------------------------------------------------
__global__ __launch_bounds__(256) void init_k(const float* __restrict__ pe_w1,
                                              const float* __restrict__ pe_w2,
                                              const float* __restrict__ ph_w1,
                                              const float* __restrict__ ph_w2,
                                              int* __restrict__ cursor,
                                              ushort_t* __restrict__ W1t,
                                              ushort_t* __restrict__ Wp1t,
                                              ushort_t* __restrict__ Wp2t,
                                              unsigned* __restrict__ w2h) {
    int gg = blockIdx.x * 256 + threadIdx.x;
    if (gg < 65536) { cursor[gg] = 0; return; }
    int g = gg - 65536;
    if (g < 16384) {
        int c = g >> 7, k = g & 127;
        float v = (c < 64) ? pe_w1[k * 64 + c] : pe_w1[(128 + k) * 64 + (c - 64)];
        W1t[g] = f2bf(v);
    } else if (g < 40960) {
        int g2 = g - 16384;
        int n = g2 / 192, k = g2 - n * 192;
        Wp1t[g2] = f2bf(ph_w1[k * 128 + n]);
    } else if (g < 57344) {
        int g3 = g - 40960;
        int n = g3 >> 7, k = g3 & 127;
        Wp2t[g3] = f2bf(ph_w2[k * 128 + n]);
    } else if (g < 59392) {
        int g4 = g - 57344;
        int k2 = g4 >> 6, c = g4 & 63;
        union { unsigned u; _Float16 h[2]; } p;
        p.h[0] = (_Float16)pe_w2[(2 * k2) * 64 + c];
        p.h[1] = (_Float16)pe_w2[(2 * k2 + 1) * 64 + c];
        w2h[g4] = p.u;
    }
}

// ---------------------------------------------------------------------------
// pgemm (blocks 0..511) + scatter (blocks 512..1535), fused launch.
// pgemm: P = h @ [W1_top|W1_mid] (bf16 out), emits hb=bf16(h) when EMIT.
// scatter: elist[gi*64 + slot] = gj (independent of pgemm; overlaps).
// ---------------------------------------------------------------------------
template <bool EMIT_BF16>
__global__ __launch_bounds__(256, 2) void pgemm_scatter_k(const float* __restrict__ A0,
                                                          const ushort_t* __restrict__ Wt,
                                                          ushort_t* __restrict__ outP,
                                                          ushort_t* __restrict__ hbout,
                                                          const int* __restrict__ ei,
                                                          int* __restrict__ cursor,
                                                          int* __restrict__ elist) {
    constexpr int KPAD = 40;
    __shared__ ushort_t As[128 * KPAD];
    __shared__ ushort_t Bs[128 * KPAD];
    const int tid = threadIdx.x;

    if (blockIdx.x >= 512) {                       // ---- scatter part
        int e = (blockIdx.x - 512) * 256 + tid;
        int2 sd = ((const int2*)ei)[e];
        int b = e >> 16;
        int gi = (b << 14) + sd.x;
        int gj = (b << 14) + sd.y;
        int slot = atomicAdd(&cursor[gi], 1);
        if (slot < 64) elist[gi * 64 + slot] = gj;
        return;
    }

    const int m0 = blockIdx.x * 128;
    const int wave = tid >> 6;
    const int lane = tid & 63;
    const int lr = lane & 15;
    const int lq = lane >> 4;

    f32x4 acc[2][8];
#pragma unroll
    for (int mt = 0; mt < 2; mt++)
#pragma unroll
        for (int nt = 0; nt < 8; nt++) { f32x4 z = {0.f,0.f,0.f,0.f}; acc[mt][nt] = z; }

    for (int k0 = 0; k0 < 128; k0 += 32) {
#pragma unroll
        for (int i = 0; i < 4; i++) {
            int lin = tid + i * 256;
            int m = lin >> 3;
            int kq = (lin & 7) * 4;
            float4 v = *(const float4*)(A0 + (size_t)(m0 + m) * 128 + k0 + kq);
            ushort4 w4;
            w4.x = f2bf(v.x); w4.y = f2bf(v.y); w4.z = f2bf(v.z); w4.w = f2bf(v.w);
            if (EMIT_BF16)
                *(ushort4*)(hbout + (size_t)(m0 + m) * 128 + k0 + kq) = w4;
            *(ushort4*)&As[m * KPAD + kq] = w4;
        }
#pragma unroll
        for (int i = 0; i < 2; i++) {
            int lin = tid + i * 256;
            int n = lin >> 2;
            int kq = (lin & 3) * 8;
            *(uint4*)&Bs[n * KPAD + kq] = *(const uint4*)(Wt + (size_t)n * 128 + k0 + kq);
        }
        __syncthreads();
        bf16x8 af[2], bfr[8];
#pragma unroll
        for (int mt = 0; mt < 2; mt++)
            af[mt] = *(const bf16x8*)&As[(wave * 32 + mt * 16 + lr) * KPAD + lq * 8];
#pragma unroll
        for (int nt = 0; nt < 8; nt++)
            bfr[nt] = *(const bf16x8*)&Bs[(nt * 16 + lr) * KPAD + lq * 8];
#pragma unroll
        for (int mt = 0; mt < 2; mt++)
#pragma unroll
            for (int nt = 0; nt < 8; nt++)
                acc[mt][nt] = __builtin_amdgcn_mfma_f32_16x16x32_bf16(af[mt], bfr[nt], acc[mt][nt], 0, 0, 0);
        __syncthreads();
    }
#pragma unroll
    for (int mt = 0; mt < 2; mt++)
#pragma unroll
        for (int nt = 0; nt < 8; nt++)
#pragma unroll
            for (int r = 0; r < 4; r++) {
                int row = m0 + wave * 32 + mt * 16 + lq * 4 + r;
                int col = nt * 16 + lr;
                outP[(size_t)row * 128 + col] = f2bf(acc[mt][nt][r]);
            }
}

// ---------------------------------------------------------------------------
// node kernel (r16 proven, 60 us): one wave per node, lane = feature,
// register prefetch of next edge's gathers.
// ---------------------------------------------------------------------------
__global__ __launch_bounds__(64, 4) void node_k(const float* __restrict__ x,
                                                const ushort_t* __restrict__ P,
                                                const int* __restrict__ cursor,
                                                const int* __restrict__ elist,
                                                const float* __restrict__ w1,
                                                const float* __restrict__ b1,
                                                const unsigned* __restrict__ w2h,
                                                const float* __restrict__ b2,
                                                const float* __restrict__ pxw,
                                                ushort_t* __restrict__ dh,
                                                float* __restrict__ outx) {
    const int n = blockIdx.x;
    const int lane = threadIdx.x;
    __shared__ __attribute__((aligned(16))) unsigned m_u[32];    // 64 halves
    ushort_t* mh = (ushort_t*)m_u;

    const float w1r = w1[256 * 64 + lane];       // dist2 row of pe_w1
    const float b2v = b2[lane];
    const float pxv = pxw[lane];
    const float Pib = bf2f(P[(size_t)n * 128 + lane]) + b1[lane];
    const float xi0 = x[n * 3 + 0];
    const float xi1 = x[n * 3 + 1];
    const float xi2 = x[n * 3 + 2];

    float dhacc = 0.0f;
    float dxp0 = 0.0f, dxp1 = 0.0f, dxp2 = 0.0f;
    const int dg = min(cursor[n], 64);
    const int base = n * 64;

    int gj0 = (dg > 0) ? elist[base] : 0;
    float Pj = bf2f(P[(size_t)gj0 * 128 + 64 + lane]);
    float xj0 = x[gj0 * 3 + 0];
    float xj1 = x[gj0 * 3 + 1];
    float xj2 = x[gj0 * 3 + 2];

    for (int t = 0; t < dg; t++) {
        int gjn = (t + 1 < dg) ? elist[base + t + 1] : 0;
        float Pjn = bf2f(P[(size_t)gjn * 128 + 64 + lane]);
        float xn0 = x[gjn * 3 + 0];
        float xn1 = x[gjn * 3 + 1];
        float xn2 = x[gjn * 3 + 2];

        float ddx = xi0 - xj0;
        float ddy = xi1 - xj1;
        float ddz = xi2 - xj2;
        float d2 = fmaxf(ddx * ddx + ddy * ddy + ddz * ddz, 1e-12f);
        float m = fast_silu(Pib + Pj + d2 * w1r);
        __builtin_amdgcn_wave_barrier();
        union { ushort_t s; _Float16 h; } mc;
        mc.h = (_Float16)m;
        mh[lane] = mc.s;
        __builtin_amdgcn_wave_barrier();
        float s0 = b2v, s1 = 0.0f, s2 = 0.0f, s3 = 0.0f;
#pragma unroll
        for (int q = 0; q < 8; q++) {
            uint4 mm = *(const uint4*)&m_u[q * 4];               // ds_read_b128 broadcast
            s0 = __builtin_amdgcn_fdot2(u2h2(mm.x), u2h2(w2h[(4 * q + 0) * 64 + lane]), s0, false);
            s1 = __builtin_amdgcn_fdot2(u2h2(mm.y), u2h2(w2h[(4 * q + 1) * 64 + lane]), s1, false);
            s2 = __builtin_amdgcn_fdot2(u2h2(mm.z), u2h2(w2h[(4 * q + 2) * 64 + lane]), s2, false);
            s3 = __builtin_amdgcn_fdot2(u2h2(mm.w), u2h2(w2h[(4 * q + 3) * 64 + lane]), s3, false);
        }
        __builtin_amdgcn_wave_barrier();
        float m2 = fast_silu((s0 + s1) + (s2 + s3));
        dhacc += m2;
        float c = m2 * pxv * fast_rcp(sqrtf(d2) + 1e-8f);
        dxp0 = fmaf(c, ddx, dxp0);
        dxp1 = fmaf(c, ddy, dxp1);
        dxp2 = fmaf(c, ddz, dxp2);

        Pj = Pjn; xj0 = xn0; xj1 = xn1; xj2 = xn2;
    }

    dh[(size_t)n * 64 + lane] = f2bf(dhacc);                 // coalesced

    for (int off = 32; off; off >>= 1) {
        dxp0 += __shfl_down(dxp0, off);
        dxp1 += __shfl_down(dxp1, off);
        dxp2 += __shfl_down(dxp2, off);
    }
    if (lane == 0) {
        outx[n * 3 + 0] = xi0 + dxp0;
        outx[n * 3 + 1] = xi1 + dxp1;
        outx[n * 3 + 2] = xi2 + dxp2;
    }
}

// ---------------------------------------------------------------------------
// Fused node MLP: out_h = h + silu([h|dh]@W1 + b1) @ W2 + b2.
// Phase 1: t(128x128) = silu([h|dh]@W1+b1) -> LDS (bf16, pad 136).
// Phase 2: out = t @ W2 + b2 + h, straight from LDS. No t round-trip to HBM.
// ---------------------------------------------------------------------------
template <bool USE_HB>
__global__ __launch_bounds__(256, 2) void mlp_fused_k(const float* __restrict__ h,
                                                      const ushort_t* __restrict__ hb,
                                                      const ushort_t* __restrict__ dh,
                                                      const ushort_t* __restrict__ Wp1t,
                                                      const float* __restrict__ b1,
                                                      const ushort_t* __restrict__ Wp2t,
                                                      const float* __restrict__ b2,
                                                      float* __restrict__ outh) {
    constexpr int KPAD = 40, TPAD = 136;
    __shared__ ushort_t As[128 * KPAD];
    __shared__ ushort_t Bs[128 * KPAD];
    __shared__ ushort_t Ts[128 * TPAD];
    const int tid = threadIdx.x;
    const int m0 = blockIdx.x * 128;
    const int wave = tid >> 6;
    const int lane = tid & 63;
    const int lr = lane & 15;
    const int lq = lane >> 4;

    f32x4 acc[2][8];
#pragma unroll
    for (int mt = 0; mt < 2; mt++)
#pragma unroll
        for (int nt = 0; nt < 8; nt++) { f32x4 z = {0.f,0.f,0.f,0.f}; acc[mt][nt] = z; }

    // ---- phase 1: t = silu([h|dh] @ W1 + b1), K = 192
    for (int k0 = 0; k0 < 192; k0 += 32) {
        if (USE_HB) {
#pragma unroll
            for (int i = 0; i < 2; i++) {
                int lin = tid + i * 256;
                int m = lin >> 2;
                int kq = (lin & 3) * 8;
                const ushort_t* src = (k0 >= 128)
                    ? dh + (size_t)(m0 + m) * 64 + (k0 - 128 + kq)
                    : hb + (size_t)(m0 + m) * 128 + k0 + kq;
                *(uint4*)&As[m * KPAD + kq] = *(const uint4*)src;
            }
        } else {
#pragma unroll
            for (int i = 0; i < 4; i++) {
                int lin = tid + i * 256;
                int m = lin >> 3;
                int kq = (lin & 7) * 4;
                ushort4 w4;
                if (k0 >= 128) {
                    w4 = *(const ushort4*)(dh + (size_t)(m0 + m) * 64 + (k0 - 128 + kq));
                } else {
                    float4 v = *(const float4*)(h + (size_t)(m0 + m) * 128 + k0 + kq);
                    w4.x = f2bf(v.x); w4.y = f2bf(v.y); w4.z = f2bf(v.z); w4.w = f2bf(v.w);
                }
                *(ushort4*)&As[m * KPAD + kq] = w4;
            }
        }
#pragma unroll
        for (int i = 0; i < 2; i++) {
            int lin = tid + i * 256;
            int n = lin >> 2;
            int kq = (lin & 3) * 8;
            *(uint4*)&Bs[n * KPAD + kq] = *(const uint4*)(Wp1t + (size_t)n * 192 + k0 + kq);
        }
        __syncthreads();
        bf16x8 af[2], bfr[8];
#pragma unroll
        for (int mt = 0; mt < 2; mt++)
            af[mt] = *(const bf16x8*)&As[(wave * 32 + mt * 16 + lr) * KPAD + lq * 8];
#pragma unroll
        for (int nt = 0; nt < 8; nt++)
            bfr[nt] = *(const bf16x8*)&Bs[(nt * 16 + lr) * KPAD + lq * 8];
#pragma unroll
        for (int mt = 0; mt < 2; mt++)
#pragma unroll
            for (int nt = 0; nt < 8; nt++)
                acc[mt][nt] = __builtin_amdgcn_mfma_f32_16x16x32_bf16(af[mt], bfr[nt], acc[mt][nt], 0, 0, 0);
        __syncthreads();
    }
    // epilogue 1: silu -> Ts (bf16)
#pragma unroll
    for (int mt = 0; mt < 2; mt++)
#pragma unroll
        for (int nt = 0; nt < 8; nt++)
#pragma unroll
            for (int r = 0; r < 4; r++) {
                int row = wave * 32 + mt * 16 + lq * 4 + r;
                int col = nt * 16 + lr;
                Ts[row * TPAD + col] = f2bf(fast_silu(acc[mt][nt][r] + b1[col]));
            }
    __syncthreads();

    // ---- phase 2: out = t @ W2 + b2 + h, K = 128, A from Ts
    f32x4 acc2[2][8];
#pragma unroll
    for (int mt = 0; mt < 2; mt++)
#pragma unroll
        for (int nt = 0; nt < 8; nt++) { f32x4 z = {0.f,0.f,0.f,0.f}; acc2[mt][nt] = z; }

    for (int k0 = 0; k0 < 128; k0 += 32) {
#pragma unroll
        for (int i = 0; i < 2; i++) {
            int lin = tid + i * 256;
            int n = lin >> 2;
            int kq = (lin & 3) * 8;
            *(uint4*)&Bs[n * KPAD + kq] = *(const uint4*)(Wp2t + (size_t)n * 128 + k0 + kq);
        }
        __syncthreads();
        bf16x8 af[2], bfr[8];
#pragma unroll
        for (int mt = 0; mt < 2; mt++)
            af[mt] = *(const bf16x8*)&Ts[(wave * 32 + mt * 16 + lr) * TPAD + k0 + lq * 8];
#pragma unroll
        for (int nt = 0; nt < 8; nt++)
            bfr[nt] = *(const bf16x8*)&Bs[(nt * 16 + lr) * KPAD + lq * 8];
#pragma unroll
        for (int mt = 0; mt < 2; mt++)
#pragma unroll
            for (int nt = 0; nt < 8; nt++)
                acc2[mt][nt] = __builtin_amdgcn_mfma_f32_16x16x32_bf16(af[mt], bfr[nt], acc2[mt][nt], 0, 0, 0);
        __syncthreads();
    }
    // epilogue 2: + b2 + h residual
#pragma unroll
    for (int mt = 0; mt < 2; mt++)
#pragma unroll
        for (int nt = 0; nt < 8; nt++)
#pragma unroll
            for (int r = 0; r < 4; r++) {
                int row = m0 + wave * 32 + mt * 16 + lq * 4 + r;
                int col = nt * 16 + lr;
                float v = acc2[mt][nt][r] + b2[col];
                if (USE_HB) v += bf2f(hb[(size_t)row * 128 + col]);
                else        v += h[(size_t)row * 128 + col];
                outh[(size_t)row * 128 + col] = v;
            }
}

// ---------------------------------------------------------------------------
extern "C" void kernel_launch(void* const* d_in, const int* in_sizes, int n_in,
                              void* d_out, int out_size, void* d_ws, size_t ws_size,
                              hipStream_t stream) {
    const float* x     = (const float*)d_in[0];
    const float* h     = (const float*)d_in[1];
    const int*   ei    = (const int*)d_in[2];
    const float* pe_w1 = (const float*)d_in[3];
    const float* pe_b1 = (const float*)d_in[4];
    const float* pe_w2 = (const float*)d_in[5];
    const float* pe_b2 = (const float*)d_in[6];
    const float* px_w  = (const float*)d_in[7];
    const float* ph_w1 = (const float*)d_in[8];
    const float* ph_b1 = (const float*)d_in[9];
    const float* ph_w2 = (const float*)d_in[10];
    const float* ph_b2 = (const float*)d_in[11];

    float* outx = (float*)d_out;                    // 4*16384*3
    float* outh = (float*)d_out + 196608;           // 4*16384*128

    // ws layout
    ushort_t* P    = (ushort_t*)d_ws;                     // 65536*128 bf16
    ushort_t* dh   = P + (size_t)65536 * 128;             // 65536*64 bf16
    int* cursor    = (int*)(dh + (size_t)65536 * 64);     // 65536 i32
    int* elist     = cursor + 65536;                      // 65536*64 i32 (16 MB)
    ushort_t* W1t  = (ushort_t*)(elist + (size_t)65536 * 64);  // 128*128 bf16
    ushort_t* Wp1t = W1t + 16384;                         // 128*192 bf16
    ushort_t* Wp2t = Wp1t + 24576;                        // 128*128 bf16
    unsigned* w2h  = (unsigned*)(Wp2t + 16384);           // 32*64 uint (in 16KB slot)
    ushort_t* hb   = (ushort_t*)(w2h + 4096);             // 65536*128 bf16 (16 MB)
    size_t need_hb = (size_t)((char*)(hb + (size_t)65536 * 128) - (char*)d_ws);
    const bool use_hb = ws_size >= need_hb;

    init_k<<<488, 256, 0, stream>>>(pe_w1, pe_w2, ph_w1, ph_w2,
                                    cursor, W1t, Wp1t, Wp2t, w2h);
    if (use_hb)
        pgemm_scatter_k<true><<<1536, 256, 0, stream>>>(h, W1t, P, hb,
                                                        ei, cursor, elist);
    else
        pgemm_scatter_k<false><<<1536, 256, 0, stream>>>(h, W1t, P, nullptr,
                                                         ei, cursor, elist);
    node_k<<<65536, 64, 0, stream>>>(x, P, cursor, elist,
                                     pe_w1, pe_b1, w2h, pe_b2, px_w,
                                     dh, outx);
    if (use_hb)
        mlp_fused_k<true><<<512, 256, 0, stream>>>(h, hb, dh, Wp1t, ph_b1,
                                                   Wp2t, ph_b2, outh);
    else
        mlp_fused_k<false><<<512, 256, 0, stream>>>(h, nullptr, dh, Wp1t, ph_b1,
                                                    Wp2t, ph_b2, outh);
}